// Round 3
// baseline (119.688 us; speedup 1.0000x reference)
//
#include <hip/hip_runtime.h>

// HadamardProj: the reference's fwht butterflies pair bit-0 every step with no
// stride change, so 2 steps = 2*I; 10 steps = 32*I; the d^-0.5 = 1/32 scaling
// cancels it. fwht == identity, hence:
//   out[b,s,d] = x[b,s,d] * scales[0][d]*...*scales[4][d]
// Pure streaming elementwise multiply: 64 MiB in + 64 MiB out => ~21 us floor.
// R1: kernel itself < 41 us (absent from top-5 vs 41us harness fills);
//     graded dur_us includes ~85-90 us of harness restore/poison traffic.
// R2: nontemporal load/store + 2x unroll. R3: use ext_vector_type(4) float
//     (native clang vector) -- __builtin_nontemporal_* rejects HIP_vector_type.

#define D_DIM 1024
#define D4 (D_DIM / 4)   // 256 float4 per row

typedef float vf4 __attribute__((ext_vector_type(4)));

__global__ __launch_bounds__(256) void hadamard_proj_kernel(
    const vf4* __restrict__ x,
    const vf4* __restrict__ scales,
    vf4*       __restrict__ out,
    int n4, int n_scales)
{
    const int tid    = blockIdx.x * blockDim.x + threadIdx.x;
    const int stride = gridDim.x * blockDim.x;   // 524288: multiple of D4, so
                                                 // d4 is invariant per thread
    const int d4 = tid & (D4 - 1);

    // Combined scale for this thread's fixed column group (registers, once).
    vf4 cs = scales[d4];
    #pragma unroll
    for (int i = 1; i < 5; ++i) {
        if (i < n_scales) {
            cs *= scales[i * D4 + d4];
        }
    }

    // n4 = 4,194,304; stride = 524,288 -> exactly 8 iterations, unroll x2.
    int i = tid;
    for (; i + stride < n4; i += 2 * stride) {
        vf4 a = __builtin_nontemporal_load(&x[i]);
        vf4 b = __builtin_nontemporal_load(&x[i + stride]);
        vf4 oa = a * cs;
        vf4 ob = b * cs;
        __builtin_nontemporal_store(oa, &out[i]);
        __builtin_nontemporal_store(ob, &out[i + stride]);
    }
    for (; i < n4; i += stride) {
        vf4 a = __builtin_nontemporal_load(&x[i]);
        vf4 oa = a * cs;
        __builtin_nontemporal_store(oa, &out[i]);
    }
}

extern "C" void kernel_launch(void* const* d_in, const int* in_sizes, int n_in,
                              void* d_out, int out_size, void* d_ws, size_t ws_size,
                              hipStream_t stream) {
    const float* x      = (const float*)d_in[0];
    const float* scales = (const float*)d_in[1];
    float*       out    = (float*)d_out;

    const int n4       = out_size / 4;            // 4,194,304 float4s
    const int n_scales = in_sizes[1] / D_DIM;     // 5

    const int block = 256;
    const int grid  = 2048;  // 8 blocks/CU on 256 CUs; 8 float4-iters/thread

    hadamard_proj_kernel<<<grid, block, 0, stream>>>(
        (const vf4*)x, (const vf4*)scales, (vf4*)out, n4, n_scales);
}

// Round 4
// 115.612 us; speedup vs baseline: 1.0353x; 1.0353x over previous
//
#include <hip/hip_runtime.h>

// HadamardProj: the reference's fwht butterflies pair bit-0 every step with no
// stride change, so 2 steps = 2*I; 10 steps = 32*I; the d^-0.5 = 1/32 scaling
// cancels it. fwht == identity, hence:
//   out[b,s,d] = x[b,s,d] * scales[0][d]*...*scales[4][d]
// Pure streaming elementwise multiply: 64 MiB in + 64 MiB out.
// R1 (113.9us graded): kernel itself <41us; ~85-90us is harness restore/poison.
// R3 (119.7us): nontemporal load/store REGRESSED ~5% -- harness pre-touches
//   x (restore) and out (poison) so both are Infinity-Cache-resident; nt bit
//   bypasses cache retention and pushes traffic to HBM. Reverted to cached
//   accesses (this file == R1 semantics).

#define D_DIM 1024
#define D4 (D_DIM / 4)   // 256 float4 per row

typedef float vf4 __attribute__((ext_vector_type(4)));

__global__ __launch_bounds__(256) void hadamard_proj_kernel(
    const vf4* __restrict__ x,
    const vf4* __restrict__ scales,
    vf4*       __restrict__ out,
    int n4, int n_scales)
{
    const int tid    = blockIdx.x * blockDim.x + threadIdx.x;
    const int stride = gridDim.x * blockDim.x;   // 524288: multiple of D4, so
                                                 // d4 is invariant per thread
    const int d4 = tid & (D4 - 1);

    // Combined scale for this thread's fixed column group (registers, once).
    vf4 cs = scales[d4];
    #pragma unroll
    for (int i = 1; i < 5; ++i) {
        if (i < n_scales) {
            cs *= scales[i * D4 + d4];
        }
    }

    // n4 = 4,194,304; stride = 524,288 -> exactly 8 iterations.
    for (int i = tid; i < n4; i += stride) {
        out[i] = x[i] * cs;
    }
}

extern "C" void kernel_launch(void* const* d_in, const int* in_sizes, int n_in,
                              void* d_out, int out_size, void* d_ws, size_t ws_size,
                              hipStream_t stream) {
    const float* x      = (const float*)d_in[0];
    const float* scales = (const float*)d_in[1];
    float*       out    = (float*)d_out;

    const int n4       = out_size / 4;            // 4,194,304 float4s
    const int n_scales = in_sizes[1] / D_DIM;     // 5

    const int block = 256;
    const int grid  = 2048;  // 8 blocks/CU on 256 CUs; 8 float4-iters/thread

    hadamard_proj_kernel<<<grid, block, 0, stream>>>(
        (const vf4*)x, (const vf4*)scales, (vf4*)out, n4, n_scales);
}